// Round 11
// baseline (377.042 us; speedup 1.0000x reference)
//
#include <hip/hip_runtime.h>

#define NN 50000
#define EE 800000
#define MM 3
#define HH 2
#define IND 128
#define HIDD 64
#define HEADD 32
#define OUTD 16
#define ATTD 128

#define NBKT 64            // fine dst-buckets per metapath
#define BSZ 782            // dsts per bucket (64*782 = 50048 >= NN)

#define NG4 200000         // EE/4 int4 groups per metapath
#define BBLK 196           // bucket blocks per metapath
#define QCAP 13200         // queue capacity per (m,bucket)

#define GLS 136            // ggl LDS row stride (u16); zl overlays as float stride 68

typedef unsigned char u8;
typedef unsigned short u16;
typedef unsigned long long u64;
typedef short bf16x8 __attribute__((ext_vector_type(8)));
typedef unsigned short u16x8 __attribute__((ext_vector_type(8)));
typedef u64 u64x2 __attribute__((ext_vector_type(2)));
typedef float f32x4 __attribute__((ext_vector_type(4)));

__device__ __forceinline__ float lrelu(float v) { return v > 0.f ? v : 0.1f * v; }

__device__ __forceinline__ float fast_tanh(float x) {
    float ax = fabsf(x);
    float e = __expf(-2.0f * ax);
    float t = (1.0f - e) * __builtin_amdgcn_rcpf(1.0f + e);
    return copysignf(t, x);
}

__device__ __forceinline__ u16 f2b(float f) {          // fp32 -> bf16 RNE
    union { float f; unsigned int u; } v; v.f = f;
    unsigned int r = v.u + 0x7fffu + ((v.u >> 16) & 1u);
    return (u16)(r >> 16);
}
__device__ __forceinline__ float b2f(u16 u) {
    union { unsigned int u; float f; } v; v.u = ((unsigned int)u) << 16; return v.f;
}

// fp32 -> e4m3 with x64 pre-scale folded in (mult by 2^6 * 2^-120 = 2^-114),
// exponent-shift trick: e4m3 bits live at f32 bits [26:20] after the scale.
__device__ __forceinline__ u8 f2e4(float f) {
    union { float f; unsigned u; } v; v.f = f * 0x1p-114f;
    unsigned s = (v.u >> 24) & 0x80u;
    unsigned b = v.u & 0x7fffffffu;
    unsigned r = b + 0x7ffffu + ((b >> 20) & 1u);     // RNE into 7-bit e4m3 payload
    return (u8)(s | ((r >> 20) & 0x7fu));
}
// e4m3 byte -> f32 * 2^-120 (caller folds 2^114 = 2^120/SCALE into the final mult)
__device__ __forceinline__ float e42f(unsigned b) {
    union { unsigned u; float f; } v;
    v.u = ((b & 0x80u) << 24) | ((b & 0x7fu) << 20);
    return v.f;
}

// ================= phase A: bucket edges into 64 fine dst-buckets =================
__global__ __launch_bounds__(256) void k_bucket(const int* __restrict__ ei,
                                                u64* __restrict__ queues,
                                                int* __restrict__ gcur) {
    __shared__ int cnt[NBKT];
    __shared__ int base[NBKT];
    const int m = blockIdx.y, tid = threadIdx.x;
    const int4* s4 = (const int4*)(ei + (size_t)m * 2 * EE);
    const int4* d4 = (const int4*)(ei + (size_t)m * 2 * EE + EE);
    const int q0 = blockIdx.x * 1024;
    if (tid < NBKT) cnt[tid] = 0;
    __syncthreads();
#pragma unroll
    for (int i = 0; i < 4; i++) {
        int q = q0 + i * 256 + tid;
        if (q < NG4) {
            int4 dv = d4[q];
            atomicAdd(&cnt[dv.x / BSZ], 1);
            atomicAdd(&cnt[dv.y / BSZ], 1);
            atomicAdd(&cnt[dv.z / BSZ], 1);
            atomicAdd(&cnt[dv.w / BSZ], 1);
        }
    }
    __syncthreads();
    if (tid < NBKT) { base[tid] = atomicAdd(&gcur[m * NBKT + tid], cnt[tid]); cnt[tid] = 0; }
    __syncthreads();
#pragma unroll
    for (int i = 0; i < 4; i++) {
        int q = q0 + i * 256 + tid;
        if (q < NG4) {
            int4 dv = d4[q];
            int4 sv = s4[q];
            int ds[4] = {dv.x, dv.y, dv.z, dv.w};
            int ss[4] = {sv.x, sv.y, sv.z, sv.w};
#pragma unroll
            for (int e = 0; e < 4; e++) {
                int b = ds[e] / BSZ;
                int slot = base[b] + atomicAdd(&cnt[b], 1);
                if (slot < QCAP) {
                    u64 pk = ((u64)(unsigned)ds[e] << 32) | (unsigned)ss[e];
                    queues[((size_t)(m * NBKT + b)) * QCAP + slot] = pk;
                }
            }
        }
    }
}

// ================= bucket-base scan (3 x 64 values) =================
__global__ void k_pscan(const int* __restrict__ gcur, int* __restrict__ pbase) {
    int t = threadIdx.x;
    if (t < MM) {
        int run = 0;
        for (int b = 0; b < NBKT; b++) {
            int L = gcur[t * NBKT + b]; if (L > QCAP) L = QCAP;
            pbase[t * NBKT + b] = run; run += L;
        }
    }
}

// ================= CSR build: one block owns one (m, bucket) =================
__global__ __launch_bounds__(512) void k_csr(const u64* __restrict__ queues,
                                             const int* __restrict__ gcur,
                                             const int* __restrict__ pbase,
                                             int* __restrict__ ofs,
                                             float* __restrict__ rs,
                                             int* __restrict__ sorted) {
    __shared__ int cnt[BSZ];
    __shared__ int wscan[8];
    const int m = blockIdx.y;
    const int b = blockIdx.x;
    const int tid = threadIdx.x;
    const int lane = tid & 63, w = tid >> 6;
    int qlen = gcur[m * NBKT + b]; if (qlen > QCAP) qlen = QCAP;
    const u64* q = queues + ((size_t)(m * NBKT + b)) * QCAP;
    const u64x2* q2 = (const u64x2*)q;
    const int dlo = b * BSZ;
    const int nd = min(dlo + BSZ, NN) - dlo;
    const int n2 = qlen >> 1;
    for (int i = tid; i < BSZ; i += 512) cnt[i] = 0;
    __syncthreads();
    for (int i = tid; i < n2; i += 512) {
        u64x2 e = q2[i];
        atomicAdd(&cnt[(int)(e.x >> 32) - dlo], 1);
        atomicAdd(&cnt[(int)(e.y >> 32) - dlo], 1);
    }
    if (tid == 0 && (qlen & 1))
        atomicAdd(&cnt[(int)(q[qlen - 1] >> 32) - dlo], 1);
    __syncthreads();
    const int c0 = tid * 2;
    int v0 = (c0 < BSZ) ? cnt[c0] : 0;
    int v1 = (c0 + 1 < BSZ) ? cnt[c0 + 1] : 0;
    int s = v0 + v1;
    int vv = s;
    for (int off = 1; off < 64; off <<= 1) { int t = __shfl_up(vv, off); if (lane >= off) vv += t; }
    if (lane == 63) wscan[w] = vv;
    __syncthreads();
    if (tid == 0) { int run = 0; for (int j = 0; j < 8; j++) { int t = wscan[j]; wscan[j] = run; run += t; } }
    __syncthreads();
    int excl = wscan[w] + vv - s;
    int g0 = pbase[m * NBKT + b] + excl;
    int g1 = g0 + v0;
    if (c0 < nd) {
        ofs[(size_t)m * (NN + 1) + dlo + c0] = g0;
        rs[(size_t)m * NN + dlo + c0] = rsqrtf((float)(v0 + 1));
    }
    if (c0 + 1 < nd) {
        ofs[(size_t)m * (NN + 1) + dlo + c0 + 1] = g1;
        rs[(size_t)m * NN + dlo + c0 + 1] = rsqrtf((float)(v1 + 1));
    }
    if (b == NBKT - 1 && tid == 0)
        ofs[(size_t)m * (NN + 1) + NN] = EE;
    __syncthreads();
    if (c0 < BSZ) cnt[c0] = g0;
    if (c0 + 1 < BSZ) cnt[c0 + 1] = g1;
    __syncthreads();
    int* srt = sorted + (size_t)m * EE;
    for (int i = tid; i < n2; i += 512) {
        u64x2 e = q2[i];
        int p0 = atomicAdd(&cnt[(int)(e.x >> 32) - dlo], 1);
        srt[p0] = (int)(e.x & 0xffffffffu);
        int p1 = atomicAdd(&cnt[(int)(e.y >> 32) - dlo], 1);
        srt[p1] = (int)(e.y & 0xffffffffu);
    }
    if (tid == 0 && (qlen & 1)) {
        u64 e = q[qlen - 1];
        int p0 = atomicAdd(&cnt[(int)(e >> 32) - dlo], 1);
        srt[p0] = (int)(e & 0xffffffffu);
    }
}

// ================= weight prep: fp32 -> bf16 MFMA B-fragment layout =================
__global__ __launch_bounds__(256) void k_prep(const float* __restrict__ We, const float* __restrict__ Wc,
                                              const float* __restrict__ Wd, const float* __restrict__ Ws,
                                              u16* __restrict__ wbe, u16* __restrict__ wbc,
                                              u16* __restrict__ wbd, u16* __restrict__ wbs) {
    int t = blockIdx.x * 256 + threadIdx.x;
    if (t >= 11776) return;
    bf16x8 val;
    u16* dst;
    if (t < 6144) {                       // enc
        int m = t >> 11, r = t & 2047;
        int nt = r >> 8, ks = (r >> 6) & 3, lane = r & 63;
        int n = nt * 16 + (lane & 15), h = n >> 6, o = n & 63;
        int kb = ks * 32 + (lane >> 4) * 8;
        const float* w = We + ((size_t)(m * 2 + h) * 128) * 64;
#pragma unroll
        for (int j = 0; j < 8; j++) val[j] = (short)f2b(w[(size_t)(kb + j) * 64 + o]);
        dst = wbe + ((size_t)m * 2048 + r) * 8;
    } else if (t < 9216) {                // conv
        int u = t - 6144;
        int m = u >> 10, r = u & 1023;
        int nt = r >> 7, ks = (r >> 6) & 1, lane = r & 63;
        int h = nt >> 2, o = (nt & 3) * 16 + (lane & 15);
        int kb = ks * 32 + (lane >> 4) * 8;
        const float* w = Wc + ((size_t)(m * 2 + h) * 64) * 64;
#pragma unroll
        for (int j = 0; j < 8; j++) val[j] = (short)f2b(w[(size_t)(kb + j) * 64 + o]);
        dst = wbc + ((size_t)m * 1024 + r) * 8;
    } else if (t < 10752) {               // dec
        int u = t - 9216;
        int m = u >> 9, r = u & 511;
        int nt = r >> 7, ks = (r >> 6) & 1, lane = r & 63;
        int h = nt >> 1, o = (nt & 1) * 16 + (lane & 15);
        int kb = ks * 32 + (lane >> 4) * 8;
        const float* w = Wd + ((size_t)(m * 2 + h) * 64) * 32;
#pragma unroll
        for (int j = 0; j < 8; j++) val[j] = (short)f2b(w[(size_t)(kb + j) * 32 + o]);
        dst = wbd + ((size_t)m * 512 + r) * 8;
    } else {                              // W_s
        int r = t - 10752;
        int nt = r >> 7, ks = (r >> 6) & 1, lane = r & 63;
        int n = nt * 16 + (lane & 15);
        int kb = ks * 32 + (lane >> 4) * 8;
#pragma unroll
        for (int j = 0; j < 8; j++) val[j] = (short)f2b(Ws[(size_t)(kb + j) * 128 + n]);
        dst = wbs + (size_t)r * 8;
    }
    *(bf16x8*)dst = val;
}

// ================= fused enc+conv: writes xw' = e4m3(64 * rs[row] * (h @ Wc)) =================
#define HLS 133
__global__ __launch_bounds__(256) void k_encconv(const float* __restrict__ x,
                                                 const u16* __restrict__ wbe_all,
                                                 const float* __restrict__ be_all,
                                                 const u16* __restrict__ wbc_all,
                                                 const float* __restrict__ rs_all,
                                                 u8* __restrict__ xw_all) {
    __shared__ float hl[64 * HLS];
    const int m = blockIdx.y;
    const int tid = threadIdx.x, lane = tid & 63, wave = tid >> 6;
    const int quad = lane >> 4, c16 = lane & 15;
    const int row = blockIdx.x * 64 + wave * 16 + c16;
    const bool ok = row < NN;
    const bf16x8* wbE = (const bf16x8*)(wbe_all + (size_t)m * 2048 * 8);
    const float* be = be_all + m * 2 * 64;
    const float* rs = rs_all + (size_t)m * NN;
    u8* xw = xw_all + (size_t)m * NN * 128;
    f32x4 zero = {0.f, 0.f, 0.f, 0.f};
    f32x4 acc[8];
#pragma unroll
    for (int nt = 0; nt < 8; nt++) acc[nt] = zero;
#pragma unroll
    for (int ks = 0; ks < 4; ks++) {
        bf16x8 a = {0, 0, 0, 0, 0, 0, 0, 0};
        if (ok) {
            const float* xp = x + (size_t)row * 128 + ks * 32 + quad * 8;
            float4 xa = *(const float4*)xp;
            float4 xb = *(const float4*)(xp + 4);
            a[0] = (short)f2b(xa.x); a[1] = (short)f2b(xa.y);
            a[2] = (short)f2b(xa.z); a[3] = (short)f2b(xa.w);
            a[4] = (short)f2b(xb.x); a[5] = (short)f2b(xb.y);
            a[6] = (short)f2b(xb.z); a[7] = (short)f2b(xb.w);
        }
#pragma unroll
        for (int nt = 0; nt < 8; nt++)
            acc[nt] = __builtin_amdgcn_mfma_f32_16x16x32_bf16(a, wbE[(nt * 4 + ks) * 64 + lane], acc[nt], 0, 0, 0);
    }
    const int rbl = wave * 16 + quad * 4;
#pragma unroll
    for (int nt = 0; nt < 8; nt++) {
        int col = nt * 16 + c16, hh = col >> 6, o = col & 63;
        float bias = be[hh * 64 + o];
#pragma unroll
        for (int j = 0; j < 4; j++) {
            int rl = rbl + j;
            int rg = blockIdx.x * 64 + rl;
            hl[rl * HLS + col] = (rg < NN) ? lrelu(acc[nt][j] + bias) : 0.f;
        }
    }
    __syncthreads();
    const bf16x8* wbC = (const bf16x8*)(wbc_all + (size_t)m * 1024 * 8);
    f32x4 cacc[8];
#pragma unroll
    for (int nt = 0; nt < 8; nt++) cacc[nt] = zero;
    const int rl = wave * 16 + c16;
#pragma unroll
    for (int ks = 0; ks < 2; ks++) {
        bf16x8 a0, a1;
        const float* hp = &hl[rl * HLS + ks * 32 + quad * 8];
#pragma unroll
        for (int j = 0; j < 8; j++) { a0[j] = (short)f2b(hp[j]); a1[j] = (short)f2b(hp[64 + j]); }
#pragma unroll
        for (int nt = 0; nt < 8; nt++)
            cacc[nt] = __builtin_amdgcn_mfma_f32_16x16x32_bf16(nt < 4 ? a0 : a1, wbC[(nt * 2 + ks) * 64 + lane], cacc[nt], 0, 0, 0);
    }
    float rsv[4];
#pragma unroll
    for (int j = 0; j < 4; j++) {
        int r = blockIdx.x * 64 + rbl + j;
        rsv[j] = (r < NN) ? rs[r] : 0.f;
    }
#pragma unroll
    for (int nt = 0; nt < 8; nt++) {
        int col = nt * 16 + c16;
#pragma unroll
        for (int j = 0; j < 4; j++) {
            int r = blockIdx.x * 64 + rbl + j;
            if (r < NN) xw[(size_t)r * 128 + col] = f2e4(cacc[nt][j] * rsv[j]);
        }
    }
}

// ================= fused gather + post + score (fp8 rows, zl overlays ggl) =================
__global__ __launch_bounds__(512) void k_gpost(const int* __restrict__ sorted_all,
                                               const int* __restrict__ ofs_all,
                                               const float* __restrict__ rs_all,
                                               const u8* __restrict__ xw_all,
                                               const float* __restrict__ bconv_all,
                                               const u16* __restrict__ wbd_all,
                                               const float* __restrict__ bdec_all,
                                               const u16* __restrict__ wbs,
                                               const float* __restrict__ bs,
                                               const float* __restrict__ qv,
                                               u16* __restrict__ z_all,
                                               float* __restrict__ score) {
    __shared__ u16 shm[64 * GLS];           // ggl (u16) / zl (float, stride 68) overlay
    __shared__ float spart[8];
    u16* ggl = shm;
    float* zl = (float*)shm;
    const int m = blockIdx.y;
    const int tid = threadIdx.x, lane = tid & 63, wave = tid >> 6;
    const int* sorted = sorted_all + (size_t)m * EE;
    const int* ofs = ofs_all + (size_t)m * (NN + 1);
    const float* rs = rs_all + (size_t)m * NN;
    const u8* xw = xw_all + (size_t)m * NN * 128;
    const float* bconv = bconv_all + m * 2 * 64;
    const float* bdec = bdec_all + m * 2 * 32;
    u16* z = z_all + (size_t)m * NN * 64;

    // ---- gather: 8 waves x 8 dsts, 4 edge-groups x 16 ch-lanes (8 fp8/lane), 2-deep ----
    const int p = lane >> 4, c = lane & 15;
    for (int d = 0; d < 8; d++) {
        int dl = wave * 8 + d;
        int dst = blockIdx.x * 64 + dl;
        if (dst < NN) {
            int beg = ofs[dst], end = ofs[dst + 1];
            float acc[8] = {0.f, 0.f, 0.f, 0.f, 0.f, 0.f, 0.f, 0.f};
            int j0 = beg + p;
            while (j0 < end) {
                int s0 = sorted[j0];
                int j1 = j0 + 4;
                bool h1 = j1 < end;
                int s1 = h1 ? sorted[j1] : s0;
                u64 w0 = *(const u64*)&xw[(size_t)s0 * 128 + c * 8];
                u64 w1 = *(const u64*)&xw[(size_t)s1 * 128 + c * 8];
#pragma unroll
                for (int k = 0; k < 8; k++) acc[k] += e42f((unsigned)(w0 >> (8 * k)) & 0xffu);
                if (h1) {
#pragma unroll
                    for (int k = 0; k < 8; k++) acc[k] += e42f((unsigned)(w1 >> (8 * k)) & 0xffu);
                }
                j0 += 8;
            }
#pragma unroll
            for (int k = 0; k < 8; k++) {
                acc[k] += __shfl_down(acc[k], 16);
                acc[k] += __shfl_down(acc[k], 32);
            }
            if (p == 0) {
                u64 ow = *(const u64*)&xw[(size_t)dst * 128 + c * 8];
                float mul = rs[dst] * 0x1p114f;   // 2^120 decode * 1/64 scale
                u16x8 o;
#pragma unroll
                for (int k = 0; k < 8; k++)
                    o[k] = f2b((acc[k] + e42f((unsigned)(ow >> (8 * k)) & 0xffu)) * mul);
                *(u16x8*)&ggl[dl * GLS + c * 8] = o;
            }
        } else if (p == 0) {
            u16x8 o = {0, 0, 0, 0, 0, 0, 0, 0};
            *(u16x8*)&ggl[dl * GLS + c * 8] = o;
        }
    }
    __syncthreads();

    // ---- post MFMA (waves 0..3): a = lrelu(ggl + bconv) @ W_dec ----
    f32x4 zero = {0.f, 0.f, 0.f, 0.f};
    const int quad = lane >> 4, c16 = lane & 15;
    f32x4 pacc[4];
#pragma unroll
    for (int nt = 0; nt < 4; nt++) pacc[nt] = zero;
    if (wave < 4) {
        const int rl = wave * 16 + c16;
        const bf16x8* wd = (const bf16x8*)(wbd_all + (size_t)m * 512 * 8);
#pragma unroll
        for (int ks = 0; ks < 2; ks++) {
            bf16x8 a0, a1;
            int k0 = ks * 32 + quad * 8;
            const u16* gp0 = &ggl[rl * GLS + k0];
            const u16* gp1 = gp0 + 64;
#pragma unroll
            for (int j = 0; j < 8; j++) {
                a0[j] = (short)f2b(lrelu(b2f(gp0[j]) + bconv[k0 + j]));
                a1[j] = (short)f2b(lrelu(b2f(gp1[j]) + bconv[64 + k0 + j]));
            }
#pragma unroll
            for (int nt = 0; nt < 4; nt++)
                pacc[nt] = __builtin_amdgcn_mfma_f32_16x16x32_bf16(nt < 2 ? a0 : a1, wd[(nt * 2 + ks) * 64 + lane], pacc[nt], 0, 0, 0);
        }
    }
    __syncthreads();   // all ggl reads done; zl may now overwrite the buffer
    if (wave < 4) {
        const int rbl = wave * 16 + quad * 4;
#pragma unroll
        for (int nt = 0; nt < 4; nt++) {
            int col = nt * 16 + c16, hh = col >> 5, o = col & 31;
            float bias = bdec[hh * 32 + o];
#pragma unroll
            for (int j = 0; j < 4; j++) {
                int rl2 = rbl + j;
                int rg = blockIdx.x * 64 + rl2;
                zl[rl2 * 68 + col] = (rg < NN) ? (pacc[nt][j] + bias) : 0.f;
            }
        }
    }
    __syncthreads();

    // ---- z store (bf16) + score MFMA (waves 0..3) ----
    float s = 0.f;
    if (wave < 4) {
        {
            int rl = tid >> 2, cq = tid & 3;
            int rg = blockIdx.x * 64 + rl;
            if (rg < NN) {
#pragma unroll
                for (int i = 0; i < 4; i++) {
                    int c4 = (cq * 4 + i) * 4;
                    float4 zv = *(const float4*)&zl[rl * 68 + c4];
                    ushort4 o;
                    o.x = f2b(zv.x); o.y = f2b(zv.y); o.z = f2b(zv.z); o.w = f2b(zv.w);
                    *(ushort4*)&z[(size_t)rg * 64 + c4] = o;
                }
            }
        }
        const bf16x8* wsb = (const bf16x8*)wbs;
        f32x4 sa[8];
#pragma unroll
        for (int nt = 0; nt < 8; nt++) sa[nt] = zero;
#pragma unroll
        for (int ks = 0; ks < 2; ks++) {
            bf16x8 a;
            const float* zp = &zl[(wave * 16 + c16) * 68 + ks * 32 + quad * 8];
#pragma unroll
            for (int j = 0; j < 8; j++) a[j] = (short)f2b(zp[j]);
#pragma unroll
            for (int nt = 0; nt < 8; nt++)
                sa[nt] = __builtin_amdgcn_mfma_f32_16x16x32_bf16(a, wsb[(nt * 2 + ks) * 64 + lane], sa[nt], 0, 0, 0);
        }
        const int rbl = wave * 16 + quad * 4;
#pragma unroll
        for (int nt = 0; nt < 8; nt++) {
            int col = nt * 16 + c16;
            float qc = qv[col], bb = bs[col];
#pragma unroll
            for (int j = 0; j < 4; j++) {
                int rg = blockIdx.x * 64 + rbl + j;
                if (rg < NN) s += fast_tanh(sa[nt][j] + bb) * qc;
            }
        }
#pragma unroll
        for (int off = 1; off < 64; off <<= 1) s += __shfl_xor(s, off);
    }
    if (lane == 0) spart[wave] = s;
    __syncthreads();
    if (tid == 0) {
        float t = spart[0] + spart[1] + spart[2] + spart[3];
        atomicAdd(&score[m], t);
    }
}

// ================= beta =================
__global__ void k_beta(const float* __restrict__ score, float* __restrict__ beta_ws,
                       float* __restrict__ out) {
    if (threadIdx.x == 0) {
        float s0 = score[0] / (float)NN, s1 = score[1] / (float)NN, s2 = score[2] / (float)NN;
        float mx = fmaxf(s0, fmaxf(s1, s2));
        float e0 = expf(s0 - mx), e1 = expf(s1 - mx), e2 = expf(s2 - mx);
        float inv = 1.f / (e0 + e1 + e2);
        beta_ws[0] = e0 * inv; beta_ws[1] = e1 * inv; beta_ws[2] = e2 * inv;
        out[800000] = e0 * inv; out[800001] = e1 * inv; out[800002] = e2 * inv;
    }
}

// ================= output: log_softmax((beta . z) @ W_o + b_o), z in bf16 =================
__global__ __launch_bounds__(256) void k_out(const u16* __restrict__ z,
                                             const float* __restrict__ beta,
                                             const float* __restrict__ Wo,
                                             const float* __restrict__ bo,
                                             float* __restrict__ out) {
    __shared__ float Zt[64 * 68];
    __shared__ float Wl[64 * 16];
    __shared__ float bl[16];
    const int tid = threadIdx.x, nbase = blockIdx.x * 64;
    float b0 = beta[0], b1 = beta[1], b2 = beta[2];
    for (int qq = tid; qq < 64 * 16; qq += 256) {
        int node = qq >> 4, k4 = qq & 15;
        int ng = nbase + node;
        float4 v = make_float4(0.f, 0.f, 0.f, 0.f);
        if (ng < NN) {
            ushort4 z0 = *(const ushort4*)&z[((size_t)0 * NN + ng) * 64 + k4 * 4];
            ushort4 z1 = *(const ushort4*)&z[((size_t)1 * NN + ng) * 64 + k4 * 4];
            ushort4 z2 = *(const ushort4*)&z[((size_t)2 * NN + ng) * 64 + k4 * 4];
            v.x = b0 * b2f(z0.x) + b1 * b2f(z1.x) + b2 * b2f(z2.x);
            v.y = b0 * b2f(z0.y) + b1 * b2f(z1.y) + b2 * b2f(z2.y);
            v.z = b0 * b2f(z0.z) + b1 * b2f(z1.z) + b2 * b2f(z2.z);
            v.w = b0 * b2f(z0.w) + b1 * b2f(z1.w) + b2 * b2f(z2.w);
        }
        *(float4*)&Zt[node * 68 + k4 * 4] = v;
    }
    for (int qq = tid; qq < 64 * 16 / 4; qq += 256)
        ((float4*)Wl)[qq] = ((const float4*)Wo)[qq];
    if (tid < 16) bl[tid] = bo[tid];
    __syncthreads();

    const int node = tid >> 2, cg = tid & 3;
    float4 a = make_float4(bl[cg * 4 + 0], bl[cg * 4 + 1], bl[cg * 4 + 2], bl[cg * 4 + 3]);
    for (int k = 0; k < 64; k++) {
        float zv = Zt[node * 68 + k];
        float4 w = *(const float4*)&Wl[k * 16 + cg * 4];
        a.x = fmaf(zv, w.x, a.x);
        a.y = fmaf(zv, w.y, a.y);
        a.z = fmaf(zv, w.z, a.z);
        a.w = fmaf(zv, w.w, a.w);
    }
    float mx = fmaxf(fmaxf(a.x, a.y), fmaxf(a.z, a.w));
    mx = fmaxf(mx, __shfl_xor(mx, 1));
    mx = fmaxf(mx, __shfl_xor(mx, 2));
    float sm = expf(a.x - mx) + expf(a.y - mx) + expf(a.z - mx) + expf(a.w - mx);
    sm += __shfl_xor(sm, 1);
    sm += __shfl_xor(sm, 2);
    float lse = mx + logf(sm);
    int ng = nbase + node;
    if (ng < NN) {
        float4 r = make_float4(a.x - lse, a.y - lse, a.z - lse, a.w - lse);
        *(float4*)&out[(size_t)ng * 16 + cg * 4] = r;
    }
}

extern "C" void kernel_launch(void* const* d_in, const int* in_sizes, int n_in,
                              void* d_out, int out_size, void* d_ws, size_t ws_size,
                              hipStream_t stream) {
    const float* x      = (const float*)d_in[0];
    const int*   ei     = (const int*)d_in[1];
    const float* W_enc  = (const float*)d_in[2];
    const float* b_enc  = (const float*)d_in[3];
    const float* W_conv = (const float*)d_in[4];
    const float* b_conv = (const float*)d_in[5];
    const float* W_dec  = (const float*)d_in[6];
    const float* b_dec  = (const float*)d_in[7];
    const float* W_s    = (const float*)d_in[8];
    const float* b_s    = (const float*)d_in[9];
    const float* qv     = (const float*)d_in[10];
    const float* W_o    = (const float*)d_in[11];
    const float* b_o    = (const float*)d_in[12];
    float* out = (float*)d_out;

    char* ws = (char*)d_ws;
    size_t off = 0;
    auto alloc = [&](size_t bytes) -> char* {
        char* p = ws + off;
        off = (off + bytes + 255) & ~(size_t)255;
        return p;
    };
    int*   row_ofs = (int*)alloc((size_t)MM * (NN + 1) * 4);
    float* rs      = (float*)alloc((size_t)MM * NN * 4);
    int*   sorted  = (int*)alloc((size_t)MM * EE * 4);
    u64*   queues  = (u64*)alloc((size_t)MM * NBKT * QCAP * 8);
    int*   gcur    = (int*)alloc((size_t)MM * NBKT * 4);
    int*   pbase   = (int*)alloc((size_t)MM * NBKT * 4);
    float* score   = (float*)alloc(64);
    float* beta_ws = (float*)alloc(64);
    u16*   wbe     = (u16*)alloc((size_t)MM * 2048 * 8 * 2);
    u16*   wbc     = (u16*)alloc((size_t)MM * 1024 * 8 * 2);
    u16*   wbd     = (u16*)alloc((size_t)MM * 512 * 8 * 2);
    u16*   wbs     = (u16*)alloc((size_t)1024 * 8 * 2);
    u8*    xw_buf  = (u8*)alloc((size_t)MM * NN * 128);     // fp8 e4m3 (x64-scaled)
    u16*   z_buf   = (u16*)alloc((size_t)MM * NN * 64 * 2);

    hipMemsetAsync(gcur, 0, (size_t)MM * NBKT * 4, stream);
    hipMemsetAsync(score, 0, 16, stream);

    dim3 gbkt(BBLK, MM);
    dim3 gcsr(NBKT, MM);
    k_bucket<<<gbkt, 256, 0, stream>>>(ei, queues, gcur);
    k_pscan<<<1, 64, 0, stream>>>(gcur, pbase);
    k_csr<<<gcsr, 512, 0, stream>>>(queues, gcur, pbase, row_ofs, rs, sorted);
    k_prep<<<46, 256, 0, stream>>>(W_enc, W_conv, W_dec, W_s, wbe, wbc, wbd, wbs);

    const int GB = (NN + 63) / 64;   // 782
    dim3 gmm(GB, MM);
    k_encconv<<<gmm, 256, 0, stream>>>(x, wbe, b_enc, wbc, rs, xw_buf);
    k_gpost<<<gmm, 512, 0, stream>>>(sorted, row_ofs, rs, xw_buf,
                                     b_conv, wbd, b_dec, wbs, b_s, qv,
                                     z_buf, score);
    k_beta<<<1, 64, 0, stream>>>(score, beta_ws, out);
    k_out<<<GB, 256, 0, stream>>>(z_buf, beta_ws, W_o, b_o, out);
}

// Round 12
// 322.992 us; speedup vs baseline: 1.1673x; 1.1673x over previous
//
#include <hip/hip_runtime.h>

#define NN 50000
#define EE 800000
#define MM 3
#define HH 2
#define IND 128
#define HIDD 64
#define HEADD 32
#define OUTD 16
#define ATTD 128

#define NBKT 64            // fine dst-buckets per metapath
#define BSZ 782            // dsts per bucket (64*782 = 50048 >= NN)

#define NG4 200000         // EE/4 int4 groups per metapath
#define BBLK 196           // bucket blocks per metapath
#define QCAP 13200         // queue capacity per (m,bucket)

#define GLS 136            // ggl LDS row stride (u16); zl overlays as float stride 68

typedef unsigned char u8;
typedef unsigned short u16;
typedef unsigned long long u64;
typedef short bf16x8 __attribute__((ext_vector_type(8)));
typedef unsigned short u16x8 __attribute__((ext_vector_type(8)));
typedef u64 u64x2 __attribute__((ext_vector_type(2)));
typedef float f32x2 __attribute__((ext_vector_type(2)));
typedef float f32x4 __attribute__((ext_vector_type(4)));

__device__ __forceinline__ float lrelu(float v) { return v > 0.f ? v : 0.1f * v; }

__device__ __forceinline__ float fast_tanh(float x) {
    float ax = fabsf(x);
    float e = __expf(-2.0f * ax);
    float t = (1.0f - e) * __builtin_amdgcn_rcpf(1.0f + e);
    return copysignf(t, x);
}

__device__ __forceinline__ u16 f2b(float f) {          // fp32 -> bf16 RNE
    union { float f; unsigned int u; } v; v.f = f;
    unsigned int r = v.u + 0x7fffu + ((v.u >> 16) & 1u);
    return (u16)(r >> 16);
}
__device__ __forceinline__ float b2f(u16 u) {
    union { unsigned int u; float f; } v; v.u = ((unsigned int)u) << 16; return v.f;
}

// hardware e4m3 encode (1 op) — value must be pre-scaled into e4m3 range
__device__ __forceinline__ u8 f2e4hw(float f) {
    int r = __builtin_amdgcn_cvt_pk_fp8_f32(f, f, 0, false);
    return (u8)(r & 0xff);
}

// ================= phase A: bucket edges into 64 fine dst-buckets =================
__global__ __launch_bounds__(256) void k_bucket(const int* __restrict__ ei,
                                                u64* __restrict__ queues,
                                                int* __restrict__ gcur) {
    __shared__ int cnt[NBKT];
    __shared__ int base[NBKT];
    const int m = blockIdx.y, tid = threadIdx.x;
    const int4* s4 = (const int4*)(ei + (size_t)m * 2 * EE);
    const int4* d4 = (const int4*)(ei + (size_t)m * 2 * EE + EE);
    const int q0 = blockIdx.x * 1024;
    if (tid < NBKT) cnt[tid] = 0;
    __syncthreads();
#pragma unroll
    for (int i = 0; i < 4; i++) {
        int q = q0 + i * 256 + tid;
        if (q < NG4) {
            int4 dv = d4[q];
            atomicAdd(&cnt[dv.x / BSZ], 1);
            atomicAdd(&cnt[dv.y / BSZ], 1);
            atomicAdd(&cnt[dv.z / BSZ], 1);
            atomicAdd(&cnt[dv.w / BSZ], 1);
        }
    }
    __syncthreads();
    if (tid < NBKT) { base[tid] = atomicAdd(&gcur[m * NBKT + tid], cnt[tid]); cnt[tid] = 0; }
    __syncthreads();
#pragma unroll
    for (int i = 0; i < 4; i++) {
        int q = q0 + i * 256 + tid;
        if (q < NG4) {
            int4 dv = d4[q];
            int4 sv = s4[q];
            int ds[4] = {dv.x, dv.y, dv.z, dv.w};
            int ss[4] = {sv.x, sv.y, sv.z, sv.w};
#pragma unroll
            for (int e = 0; e < 4; e++) {
                int b = ds[e] / BSZ;
                int slot = base[b] + atomicAdd(&cnt[b], 1);
                if (slot < QCAP) {
                    u64 pk = ((u64)(unsigned)ds[e] << 32) | (unsigned)ss[e];
                    queues[((size_t)(m * NBKT + b)) * QCAP + slot] = pk;
                }
            }
        }
    }
}

// ================= bucket-base scan (3 x 64 values) =================
__global__ void k_pscan(const int* __restrict__ gcur, int* __restrict__ pbase) {
    int t = threadIdx.x;
    if (t < MM) {
        int run = 0;
        for (int b = 0; b < NBKT; b++) {
            int L = gcur[t * NBKT + b]; if (L > QCAP) L = QCAP;
            pbase[t * NBKT + b] = run; run += L;
        }
    }
}

// ================= CSR build: one block owns one (m, bucket) =================
__global__ __launch_bounds__(512) void k_csr(const u64* __restrict__ queues,
                                             const int* __restrict__ gcur,
                                             const int* __restrict__ pbase,
                                             int* __restrict__ ofs,
                                             float* __restrict__ rs,
                                             int* __restrict__ sorted) {
    __shared__ int cnt[BSZ];
    __shared__ int wscan[8];
    const int m = blockIdx.y;
    const int b = blockIdx.x;
    const int tid = threadIdx.x;
    const int lane = tid & 63, w = tid >> 6;
    int qlen = gcur[m * NBKT + b]; if (qlen > QCAP) qlen = QCAP;
    const u64* q = queues + ((size_t)(m * NBKT + b)) * QCAP;
    const u64x2* q2 = (const u64x2*)q;
    const int dlo = b * BSZ;
    const int nd = min(dlo + BSZ, NN) - dlo;
    const int n2 = qlen >> 1;
    for (int i = tid; i < BSZ; i += 512) cnt[i] = 0;
    __syncthreads();
    for (int i = tid; i < n2; i += 512) {
        u64x2 e = q2[i];
        atomicAdd(&cnt[(int)(e.x >> 32) - dlo], 1);
        atomicAdd(&cnt[(int)(e.y >> 32) - dlo], 1);
    }
    if (tid == 0 && (qlen & 1))
        atomicAdd(&cnt[(int)(q[qlen - 1] >> 32) - dlo], 1);
    __syncthreads();
    const int c0 = tid * 2;
    int v0 = (c0 < BSZ) ? cnt[c0] : 0;
    int v1 = (c0 + 1 < BSZ) ? cnt[c0 + 1] : 0;
    int s = v0 + v1;
    int vv = s;
    for (int off = 1; off < 64; off <<= 1) { int t = __shfl_up(vv, off); if (lane >= off) vv += t; }
    if (lane == 63) wscan[w] = vv;
    __syncthreads();
    if (tid == 0) { int run = 0; for (int j = 0; j < 8; j++) { int t = wscan[j]; wscan[j] = run; run += t; } }
    __syncthreads();
    int excl = wscan[w] + vv - s;
    int g0 = pbase[m * NBKT + b] + excl;
    int g1 = g0 + v0;
    if (c0 < nd) {
        ofs[(size_t)m * (NN + 1) + dlo + c0] = g0;
        rs[(size_t)m * NN + dlo + c0] = rsqrtf((float)(v0 + 1));
    }
    if (c0 + 1 < nd) {
        ofs[(size_t)m * (NN + 1) + dlo + c0 + 1] = g1;
        rs[(size_t)m * NN + dlo + c0 + 1] = rsqrtf((float)(v1 + 1));
    }
    if (b == NBKT - 1 && tid == 0)
        ofs[(size_t)m * (NN + 1) + NN] = EE;
    __syncthreads();
    if (c0 < BSZ) cnt[c0] = g0;
    if (c0 + 1 < BSZ) cnt[c0 + 1] = g1;
    __syncthreads();
    int* srt = sorted + (size_t)m * EE;
    for (int i = tid; i < n2; i += 512) {
        u64x2 e = q2[i];
        int p0 = atomicAdd(&cnt[(int)(e.x >> 32) - dlo], 1);
        srt[p0] = (int)(e.x & 0xffffffffu);
        int p1 = atomicAdd(&cnt[(int)(e.y >> 32) - dlo], 1);
        srt[p1] = (int)(e.y & 0xffffffffu);
    }
    if (tid == 0 && (qlen & 1)) {
        u64 e = q[qlen - 1];
        int p0 = atomicAdd(&cnt[(int)(e >> 32) - dlo], 1);
        srt[p0] = (int)(e & 0xffffffffu);
    }
}

// ================= weight prep: fp32 -> bf16 MFMA B-fragment layout =================
__global__ __launch_bounds__(256) void k_prep(const float* __restrict__ We, const float* __restrict__ Wc,
                                              const float* __restrict__ Wd, const float* __restrict__ Ws,
                                              u16* __restrict__ wbe, u16* __restrict__ wbc,
                                              u16* __restrict__ wbd, u16* __restrict__ wbs) {
    int t = blockIdx.x * 256 + threadIdx.x;
    if (t >= 11776) return;
    bf16x8 val;
    u16* dst;
    if (t < 6144) {                       // enc
        int m = t >> 11, r = t & 2047;
        int nt = r >> 8, ks = (r >> 6) & 3, lane = r & 63;
        int n = nt * 16 + (lane & 15), h = n >> 6, o = n & 63;
        int kb = ks * 32 + (lane >> 4) * 8;
        const float* w = We + ((size_t)(m * 2 + h) * 128) * 64;
#pragma unroll
        for (int j = 0; j < 8; j++) val[j] = (short)f2b(w[(size_t)(kb + j) * 64 + o]);
        dst = wbe + ((size_t)m * 2048 + r) * 8;
    } else if (t < 9216) {                // conv
        int u = t - 6144;
        int m = u >> 10, r = u & 1023;
        int nt = r >> 7, ks = (r >> 6) & 1, lane = r & 63;
        int h = nt >> 2, o = (nt & 3) * 16 + (lane & 15);
        int kb = ks * 32 + (lane >> 4) * 8;
        const float* w = Wc + ((size_t)(m * 2 + h) * 64) * 64;
#pragma unroll
        for (int j = 0; j < 8; j++) val[j] = (short)f2b(w[(size_t)(kb + j) * 64 + o]);
        dst = wbc + ((size_t)m * 1024 + r) * 8;
    } else if (t < 10752) {               // dec
        int u = t - 9216;
        int m = u >> 9, r = u & 511;
        int nt = r >> 7, ks = (r >> 6) & 1, lane = r & 63;
        int h = nt >> 1, o = (nt & 1) * 16 + (lane & 15);
        int kb = ks * 32 + (lane >> 4) * 8;
        const float* w = Wd + ((size_t)(m * 2 + h) * 64) * 32;
#pragma unroll
        for (int j = 0; j < 8; j++) val[j] = (short)f2b(w[(size_t)(kb + j) * 32 + o]);
        dst = wbd + ((size_t)m * 512 + r) * 8;
    } else {                              // W_s
        int r = t - 10752;
        int nt = r >> 7, ks = (r >> 6) & 1, lane = r & 63;
        int n = nt * 16 + (lane & 15);
        int kb = ks * 32 + (lane >> 4) * 8;
#pragma unroll
        for (int j = 0; j < 8; j++) val[j] = (short)f2b(Ws[(size_t)(kb + j) * 128 + n]);
        dst = wbs + (size_t)r * 8;
    }
    *(bf16x8*)dst = val;
}

// ================= fused enc+conv: writes xw' = e4m3(64 * rs[row] * (h @ Wc)) =================
#define HLS 133
__global__ __launch_bounds__(256) void k_encconv(const float* __restrict__ x,
                                                 const u16* __restrict__ wbe_all,
                                                 const float* __restrict__ be_all,
                                                 const u16* __restrict__ wbc_all,
                                                 const float* __restrict__ rs_all,
                                                 u8* __restrict__ xw_all) {
    __shared__ float hl[64 * HLS];
    const int m = blockIdx.y;
    const int tid = threadIdx.x, lane = tid & 63, wave = tid >> 6;
    const int quad = lane >> 4, c16 = lane & 15;
    const int row = blockIdx.x * 64 + wave * 16 + c16;
    const bool ok = row < NN;
    const bf16x8* wbE = (const bf16x8*)(wbe_all + (size_t)m * 2048 * 8);
    const float* be = be_all + m * 2 * 64;
    const float* rs = rs_all + (size_t)m * NN;
    u8* xw = xw_all + (size_t)m * NN * 128;
    f32x4 zero = {0.f, 0.f, 0.f, 0.f};
    f32x4 acc[8];
#pragma unroll
    for (int nt = 0; nt < 8; nt++) acc[nt] = zero;
#pragma unroll
    for (int ks = 0; ks < 4; ks++) {
        bf16x8 a = {0, 0, 0, 0, 0, 0, 0, 0};
        if (ok) {
            const float* xp = x + (size_t)row * 128 + ks * 32 + quad * 8;
            float4 xa = *(const float4*)xp;
            float4 xb = *(const float4*)(xp + 4);
            a[0] = (short)f2b(xa.x); a[1] = (short)f2b(xa.y);
            a[2] = (short)f2b(xa.z); a[3] = (short)f2b(xa.w);
            a[4] = (short)f2b(xb.x); a[5] = (short)f2b(xb.y);
            a[6] = (short)f2b(xb.z); a[7] = (short)f2b(xb.w);
        }
#pragma unroll
        for (int nt = 0; nt < 8; nt++)
            acc[nt] = __builtin_amdgcn_mfma_f32_16x16x32_bf16(a, wbE[(nt * 4 + ks) * 64 + lane], acc[nt], 0, 0, 0);
    }
    const int rbl = wave * 16 + quad * 4;
#pragma unroll
    for (int nt = 0; nt < 8; nt++) {
        int col = nt * 16 + c16, hh = col >> 6, o = col & 63;
        float bias = be[hh * 64 + o];
#pragma unroll
        for (int j = 0; j < 4; j++) {
            int rl = rbl + j;
            int rg = blockIdx.x * 64 + rl;
            hl[rl * HLS + col] = (rg < NN) ? lrelu(acc[nt][j] + bias) : 0.f;
        }
    }
    __syncthreads();
    const bf16x8* wbC = (const bf16x8*)(wbc_all + (size_t)m * 1024 * 8);
    f32x4 cacc[8];
#pragma unroll
    for (int nt = 0; nt < 8; nt++) cacc[nt] = zero;
    const int rl = wave * 16 + c16;
#pragma unroll
    for (int ks = 0; ks < 2; ks++) {
        bf16x8 a0, a1;
        const float* hp = &hl[rl * HLS + ks * 32 + quad * 8];
#pragma unroll
        for (int j = 0; j < 8; j++) { a0[j] = (short)f2b(hp[j]); a1[j] = (short)f2b(hp[64 + j]); }
#pragma unroll
        for (int nt = 0; nt < 8; nt++)
            cacc[nt] = __builtin_amdgcn_mfma_f32_16x16x32_bf16(nt < 4 ? a0 : a1, wbC[(nt * 2 + ks) * 64 + lane], cacc[nt], 0, 0, 0);
    }
    float rsv[4];
#pragma unroll
    for (int j = 0; j < 4; j++) {
        int r = blockIdx.x * 64 + rbl + j;
        rsv[j] = (r < NN) ? rs[r] * 64.f : 0.f;
    }
#pragma unroll
    for (int nt = 0; nt < 8; nt++) {
        int col = nt * 16 + c16;
#pragma unroll
        for (int j = 0; j < 4; j++) {
            int r = blockIdx.x * 64 + rbl + j;
            if (r < NN) xw[(size_t)r * 128 + col] = f2e4hw(cacc[nt][j] * rsv[j]);
        }
    }
}

// decode 8 fp8 bytes (u64) into 4 f32x2 partial accumulators via hw cvt
__device__ __forceinline__ void acc_fp8x8(f32x2* acc, u64 w) {
    unsigned lo = (unsigned)w, hi = (unsigned)(w >> 32);
    acc[0] += __builtin_amdgcn_cvt_pk_f32_fp8(lo, false);
    acc[1] += __builtin_amdgcn_cvt_pk_f32_fp8(lo, true);
    acc[2] += __builtin_amdgcn_cvt_pk_f32_fp8(hi, false);
    acc[3] += __builtin_amdgcn_cvt_pk_f32_fp8(hi, true);
}

// ================= fused gather + post + score (fp8 rows, hw cvt, zl overlays ggl) =================
__global__ __launch_bounds__(512) void k_gpost(const int* __restrict__ sorted_all,
                                               const int* __restrict__ ofs_all,
                                               const float* __restrict__ rs_all,
                                               const u8* __restrict__ xw_all,
                                               const float* __restrict__ bconv_all,
                                               const u16* __restrict__ wbd_all,
                                               const float* __restrict__ bdec_all,
                                               const u16* __restrict__ wbs,
                                               const float* __restrict__ bs,
                                               const float* __restrict__ qv,
                                               u16* __restrict__ z_all,
                                               float* __restrict__ score) {
    __shared__ u16 shm[64 * GLS];           // ggl (u16) / zl (float, stride 68) overlay
    __shared__ float spart[8];
    u16* ggl = shm;
    float* zl = (float*)shm;
    const int m = blockIdx.y;
    const int tid = threadIdx.x, lane = tid & 63, wave = tid >> 6;
    const int* sorted = sorted_all + (size_t)m * EE;
    const int* ofs = ofs_all + (size_t)m * (NN + 1);
    const float* rs = rs_all + (size_t)m * NN;
    const u8* xw = xw_all + (size_t)m * NN * 128;
    const float* bconv = bconv_all + m * 2 * 64;
    const float* bdec = bdec_all + m * 2 * 32;
    u16* z = z_all + (size_t)m * NN * 64;

    // ---- gather: 8 waves x 8 dsts, 4 edge-groups x 16 ch-lanes (8 fp8/lane), 4-deep ----
    const int p = lane >> 4, c = lane & 15;
    for (int d = 0; d < 8; d++) {
        int dl = wave * 8 + d;
        int dst = blockIdx.x * 64 + dl;
        if (dst < NN) {
            int beg = ofs[dst], end = ofs[dst + 1];
            f32x2 acc[4];
            acc[0] = 0.f; acc[1] = 0.f; acc[2] = 0.f; acc[3] = 0.f;
            int j0 = beg + p;
            while (j0 < end) {
                int j1 = j0 + 4, j2 = j0 + 8, j3 = j0 + 12;
                bool h1 = j1 < end, h2 = j2 < end, h3 = j3 < end;
                int s0 = sorted[j0];
                int s1 = h1 ? sorted[j1] : s0;
                int s2 = h2 ? sorted[j2] : s0;
                int s3 = h3 ? sorted[j3] : s0;
                u64 w0 = *(const u64*)&xw[(size_t)s0 * 128 + c * 8];
                u64 w1 = *(const u64*)&xw[(size_t)s1 * 128 + c * 8];
                u64 w2 = *(const u64*)&xw[(size_t)s2 * 128 + c * 8];
                u64 w3 = *(const u64*)&xw[(size_t)s3 * 128 + c * 8];
                acc_fp8x8(acc, w0);
                if (h1) acc_fp8x8(acc, w1);
                if (h2) acc_fp8x8(acc, w2);
                if (h3) acc_fp8x8(acc, w3);
                j0 += 16;
            }
#pragma unroll
            for (int k = 0; k < 4; k++) {
                acc[k].x += __shfl_down(acc[k].x, 16);
                acc[k].y += __shfl_down(acc[k].y, 16);
                acc[k].x += __shfl_down(acc[k].x, 32);
                acc[k].y += __shfl_down(acc[k].y, 32);
            }
            if (p == 0) {
                u64 ow = *(const u64*)&xw[(size_t)dst * 128 + c * 8];
                acc_fp8x8(acc, ow);
                float mul = rs[dst] * (1.f / 64.f);
                u16x8 o;
#pragma unroll
                for (int k = 0; k < 4; k++) {
                    o[2 * k] = f2b(acc[k].x * mul);
                    o[2 * k + 1] = f2b(acc[k].y * mul);
                }
                *(u16x8*)&ggl[dl * GLS + c * 8] = o;
            }
        } else if (p == 0) {
            u16x8 o = {0, 0, 0, 0, 0, 0, 0, 0};
            *(u16x8*)&ggl[dl * GLS + c * 8] = o;
        }
    }
    __syncthreads();

    // ---- post MFMA (waves 0..3): a = lrelu(ggl + bconv) @ W_dec ----
    f32x4 zero = {0.f, 0.f, 0.f, 0.f};
    const int quad = lane >> 4, c16 = lane & 15;
    f32x4 pacc[4];
#pragma unroll
    for (int nt = 0; nt < 4; nt++) pacc[nt] = zero;
    if (wave < 4) {
        const int rl = wave * 16 + c16;
        const bf16x8* wd = (const bf16x8*)(wbd_all + (size_t)m * 512 * 8);
#pragma unroll
        for (int ks = 0; ks < 2; ks++) {
            bf16x8 a0, a1;
            int k0 = ks * 32 + quad * 8;
            const u16* gp0 = &ggl[rl * GLS + k0];
            const u16* gp1 = gp0 + 64;
#pragma unroll
            for (int j = 0; j < 8; j++) {
                a0[j] = (short)f2b(lrelu(b2f(gp0[j]) + bconv[k0 + j]));
                a1[j] = (short)f2b(lrelu(b2f(gp1[j]) + bconv[64 + k0 + j]));
            }
#pragma unroll
            for (int nt = 0; nt < 4; nt++)
                pacc[nt] = __builtin_amdgcn_mfma_f32_16x16x32_bf16(nt < 2 ? a0 : a1, wd[(nt * 2 + ks) * 64 + lane], pacc[nt], 0, 0, 0);
        }
    }
    __syncthreads();   // all ggl reads done; zl may now overwrite the buffer
    if (wave < 4) {
        const int rbl = wave * 16 + quad * 4;
#pragma unroll
        for (int nt = 0; nt < 4; nt++) {
            int col = nt * 16 + c16, hh = col >> 5, o = col & 31;
            float bias = bdec[hh * 32 + o];
#pragma unroll
            for (int j = 0; j < 4; j++) {
                int rl2 = rbl + j;
                int rg = blockIdx.x * 64 + rl2;
                zl[rl2 * 68 + col] = (rg < NN) ? (pacc[nt][j] + bias) : 0.f;
            }
        }
    }
    __syncthreads();

    // ---- z store (bf16) + score MFMA (waves 0..3) ----
    float s = 0.f;
    if (wave < 4) {
        {
            int rl = tid >> 2, cq = tid & 3;
            int rg = blockIdx.x * 64 + rl;
            if (rg < NN) {
#pragma unroll
                for (int i = 0; i < 4; i++) {
                    int c4 = (cq * 4 + i) * 4;
                    float4 zv = *(const float4*)&zl[rl * 68 + c4];
                    ushort4 o;
                    o.x = f2b(zv.x); o.y = f2b(zv.y); o.z = f2b(zv.z); o.w = f2b(zv.w);
                    *(ushort4*)&z[(size_t)rg * 64 + c4] = o;
                }
            }
        }
        const bf16x8* wsb = (const bf16x8*)wbs;
        f32x4 sa[8];
#pragma unroll
        for (int nt = 0; nt < 8; nt++) sa[nt] = zero;
#pragma unroll
        for (int ks = 0; ks < 2; ks++) {
            bf16x8 a;
            const float* zp = &zl[(wave * 16 + c16) * 68 + ks * 32 + quad * 8];
#pragma unroll
            for (int j = 0; j < 8; j++) a[j] = (short)f2b(zp[j]);
#pragma unroll
            for (int nt = 0; nt < 8; nt++)
                sa[nt] = __builtin_amdgcn_mfma_f32_16x16x32_bf16(a, wsb[(nt * 2 + ks) * 64 + lane], sa[nt], 0, 0, 0);
        }
        const int rbl = wave * 16 + quad * 4;
#pragma unroll
        for (int nt = 0; nt < 8; nt++) {
            int col = nt * 16 + c16;
            float qc = qv[col], bb = bs[col];
#pragma unroll
            for (int j = 0; j < 4; j++) {
                int rg = blockIdx.x * 64 + rbl + j;
                if (rg < NN) s += fast_tanh(sa[nt][j] + bb) * qc;
            }
        }
#pragma unroll
        for (int off = 1; off < 64; off <<= 1) s += __shfl_xor(s, off);
    }
    if (lane == 0) spart[wave] = s;
    __syncthreads();
    if (tid == 0) {
        float t = spart[0] + spart[1] + spart[2] + spart[3];
        atomicAdd(&score[m], t);
    }
}

// ================= beta =================
__global__ void k_beta(const float* __restrict__ score, float* __restrict__ beta_ws,
                       float* __restrict__ out) {
    if (threadIdx.x == 0) {
        float s0 = score[0] / (float)NN, s1 = score[1] / (float)NN, s2 = score[2] / (float)NN;
        float mx = fmaxf(s0, fmaxf(s1, s2));
        float e0 = expf(s0 - mx), e1 = expf(s1 - mx), e2 = expf(s2 - mx);
        float inv = 1.f / (e0 + e1 + e2);
        beta_ws[0] = e0 * inv; beta_ws[1] = e1 * inv; beta_ws[2] = e2 * inv;
        out[800000] = e0 * inv; out[800001] = e1 * inv; out[800002] = e2 * inv;
    }
}

// ================= output: log_softmax((beta . z) @ W_o + b_o), z in bf16 =================
__global__ __launch_bounds__(256) void k_out(const u16* __restrict__ z,
                                             const float* __restrict__ beta,
                                             const float* __restrict__ Wo,
                                             const float* __restrict__ bo,
                                             float* __restrict__ out) {
    __shared__ float Zt[64 * 68];
    __shared__ float Wl[64 * 16];
    __shared__ float bl[16];
    const int tid = threadIdx.x, nbase = blockIdx.x * 64;
    float b0 = beta[0], b1 = beta[1], b2 = beta[2];
    for (int qq = tid; qq < 64 * 16; qq += 256) {
        int node = qq >> 4, k4 = qq & 15;
        int ng = nbase + node;
        float4 v = make_float4(0.f, 0.f, 0.f, 0.f);
        if (ng < NN) {
            ushort4 z0 = *(const ushort4*)&z[((size_t)0 * NN + ng) * 64 + k4 * 4];
            ushort4 z1 = *(const ushort4*)&z[((size_t)1 * NN + ng) * 64 + k4 * 4];
            ushort4 z2 = *(const ushort4*)&z[((size_t)2 * NN + ng) * 64 + k4 * 4];
            v.x = b0 * b2f(z0.x) + b1 * b2f(z1.x) + b2 * b2f(z2.x);
            v.y = b0 * b2f(z0.y) + b1 * b2f(z1.y) + b2 * b2f(z2.y);
            v.z = b0 * b2f(z0.z) + b1 * b2f(z1.z) + b2 * b2f(z2.z);
            v.w = b0 * b2f(z0.w) + b1 * b2f(z1.w) + b2 * b2f(z2.w);
        }
        *(float4*)&Zt[node * 68 + k4 * 4] = v;
    }
    for (int qq = tid; qq < 64 * 16 / 4; qq += 256)
        ((float4*)Wl)[qq] = ((const float4*)Wo)[qq];
    if (tid < 16) bl[tid] = bo[tid];
    __syncthreads();

    const int node = tid >> 2, cg = tid & 3;
    float4 a = make_float4(bl[cg * 4 + 0], bl[cg * 4 + 1], bl[cg * 4 + 2], bl[cg * 4 + 3]);
    for (int k = 0; k < 64; k++) {
        float zv = Zt[node * 68 + k];
        float4 w = *(const float4*)&Wl[k * 16 + cg * 4];
        a.x = fmaf(zv, w.x, a.x);
        a.y = fmaf(zv, w.y, a.y);
        a.z = fmaf(zv, w.z, a.z);
        a.w = fmaf(zv, w.w, a.w);
    }
    float mx = fmaxf(fmaxf(a.x, a.y), fmaxf(a.z, a.w));
    mx = fmaxf(mx, __shfl_xor(mx, 1));
    mx = fmaxf(mx, __shfl_xor(mx, 2));
    float sm = expf(a.x - mx) + expf(a.y - mx) + expf(a.z - mx) + expf(a.w - mx);
    sm += __shfl_xor(sm, 1);
    sm += __shfl_xor(sm, 2);
    float lse = mx + logf(sm);
    int ng = nbase + node;
    if (ng < NN) {
        float4 r = make_float4(a.x - lse, a.y - lse, a.z - lse, a.w - lse);
        *(float4*)&out[(size_t)ng * 16 + cg * 4] = r;
    }
}

extern "C" void kernel_launch(void* const* d_in, const int* in_sizes, int n_in,
                              void* d_out, int out_size, void* d_ws, size_t ws_size,
                              hipStream_t stream) {
    const float* x      = (const float*)d_in[0];
    const int*   ei     = (const int*)d_in[1];
    const float* W_enc  = (const float*)d_in[2];
    const float* b_enc  = (const float*)d_in[3];
    const float* W_conv = (const float*)d_in[4];
    const float* b_conv = (const float*)d_in[5];
    const float* W_dec  = (const float*)d_in[6];
    const float* b_dec  = (const float*)d_in[7];
    const float* W_s    = (const float*)d_in[8];
    const float* b_s    = (const float*)d_in[9];
    const float* qv     = (const float*)d_in[10];
    const float* W_o    = (const float*)d_in[11];
    const float* b_o    = (const float*)d_in[12];
    float* out = (float*)d_out;

    char* ws = (char*)d_ws;
    size_t off = 0;
    auto alloc = [&](size_t bytes) -> char* {
        char* p = ws + off;
        off = (off + bytes + 255) & ~(size_t)255;
        return p;
    };
    int*   row_ofs = (int*)alloc((size_t)MM * (NN + 1) * 4);
    float* rs      = (float*)alloc((size_t)MM * NN * 4);
    int*   sorted  = (int*)alloc((size_t)MM * EE * 4);
    u64*   queues  = (u64*)alloc((size_t)MM * NBKT * QCAP * 8);
    int*   gcur    = (int*)alloc((size_t)MM * NBKT * 4);
    int*   pbase   = (int*)alloc((size_t)MM * NBKT * 4);
    float* score   = (float*)alloc(64);
    float* beta_ws = (float*)alloc(64);
    u16*   wbe     = (u16*)alloc((size_t)MM * 2048 * 8 * 2);
    u16*   wbc     = (u16*)alloc((size_t)MM * 1024 * 8 * 2);
    u16*   wbd     = (u16*)alloc((size_t)MM * 512 * 8 * 2);
    u16*   wbs     = (u16*)alloc((size_t)1024 * 8 * 2);
    u8*    xw_buf  = (u8*)alloc((size_t)MM * NN * 128);     // fp8 e4m3 (x64-scaled)
    u16*   z_buf   = (u16*)alloc((size_t)MM * NN * 64 * 2);

    hipMemsetAsync(gcur, 0, (size_t)MM * NBKT * 4, stream);
    hipMemsetAsync(score, 0, 16, stream);

    dim3 gbkt(BBLK, MM);
    dim3 gcsr(NBKT, MM);
    k_bucket<<<gbkt, 256, 0, stream>>>(ei, queues, gcur);
    k_pscan<<<1, 64, 0, stream>>>(gcur, pbase);
    k_csr<<<gcsr, 512, 0, stream>>>(queues, gcur, pbase, row_ofs, rs, sorted);
    k_prep<<<46, 256, 0, stream>>>(W_enc, W_conv, W_dec, W_s, wbe, wbc, wbd, wbs);

    const int GB = (NN + 63) / 64;   // 782
    dim3 gmm(GB, MM);
    k_encconv<<<gmm, 256, 0, stream>>>(x, wbe, b_enc, wbc, rs, xw_buf);
    k_gpost<<<gmm, 512, 0, stream>>>(sorted, row_ofs, rs, xw_buf,
                                     b_conv, wbd, b_dec, wbs, b_s, qv,
                                     z_buf, score);
    k_beta<<<1, 64, 0, stream>>>(score, beta_ws, out);
    k_out<<<GB, 256, 0, stream>>>(z_buf, beta_ws, W_o, b_o, out);
}

// Round 13
// 276.547 us; speedup vs baseline: 1.3634x; 1.1679x over previous
//
#include <hip/hip_runtime.h>

#define NN 50000
#define EE 800000
#define MM 3
#define HH 2
#define IND 128
#define HIDD 64
#define HEADD 32
#define OUTD 16
#define ATTD 128

#define NBKT 64
#define BSZ 782

#define NG4 200000
#define BBLK 196
#define QCAP 13200

#define GLS 136            // ggl LDS row stride (u16); zl overlays as float stride 68

typedef unsigned char u8;
typedef unsigned short u16;
typedef unsigned long long u64;
typedef short bf16x8 __attribute__((ext_vector_type(8)));
typedef unsigned short u16x8 __attribute__((ext_vector_type(8)));
typedef u64 u64x2 __attribute__((ext_vector_type(2)));
typedef float f32x2 __attribute__((ext_vector_type(2)));
typedef float f32x4 __attribute__((ext_vector_type(4)));

__device__ __forceinline__ float lrelu(float v) { return v > 0.f ? v : 0.1f * v; }

__device__ __forceinline__ float fast_tanh(float x) {
    float ax = fabsf(x);
    float e = __expf(-2.0f * ax);
    float t = (1.0f - e) * __builtin_amdgcn_rcpf(1.0f + e);
    return copysignf(t, x);
}

__device__ __forceinline__ u16 f2b(float f) {          // fp32 -> bf16 RNE
    union { float f; unsigned int u; } v; v.f = f;
    unsigned int r = v.u + 0x7fffu + ((v.u >> 16) & 1u);
    return (u16)(r >> 16);
}
__device__ __forceinline__ float b2f(u16 u) {
    union { unsigned int u; float f; } v; v.u = ((unsigned int)u) << 16; return v.f;
}

__device__ __forceinline__ u8 f2e4hw(float f) {
    int r = __builtin_amdgcn_cvt_pk_fp8_f32(f, f, 0, false);
    return (u8)(r & 0xff);
}

// ================= phase A: bucket edges into 64 fine dst-buckets =================
__global__ __launch_bounds__(256) void k_bucket(const int* __restrict__ ei,
                                                u64* __restrict__ queues,
                                                int* __restrict__ gcur) {
    __shared__ int cnt[NBKT];
    __shared__ int base[NBKT];
    const int m = blockIdx.y, tid = threadIdx.x;
    const int4* s4 = (const int4*)(ei + (size_t)m * 2 * EE);
    const int4* d4 = (const int4*)(ei + (size_t)m * 2 * EE + EE);
    const int q0 = blockIdx.x * 1024;
    if (tid < NBKT) cnt[tid] = 0;
    __syncthreads();
#pragma unroll
    for (int i = 0; i < 4; i++) {
        int q = q0 + i * 256 + tid;
        if (q < NG4) {
            int4 v = d4[q];
            atomicAdd(&cnt[v.x / BSZ], 1);
            atomicAdd(&cnt[v.y / BSZ], 1);
            atomicAdd(&cnt[v.z / BSZ], 1);
            atomicAdd(&cnt[v.w / BSZ], 1);
        }
    }
    __syncthreads();
    if (tid < NBKT) { base[tid] = atomicAdd(&gcur[m * NBKT + tid], cnt[tid]); cnt[tid] = 0; }
    __syncthreads();
#pragma unroll
    for (int i = 0; i < 4; i++) {
        int q = q0 + i * 256 + tid;
        if (q < NG4) {
            int4 dv = d4[q];
            int4 sv = s4[q];
            int ds[4] = {dv.x, dv.y, dv.z, dv.w};
            int ss[4] = {sv.x, sv.y, sv.z, sv.w};
#pragma unroll
            for (int e = 0; e < 4; e++) {
                int b = ds[e] / BSZ;
                int slot = base[b] + atomicAdd(&cnt[b], 1);
                if (slot < QCAP) {
                    u64 pk = ((u64)(unsigned)ds[e] << 32) | (unsigned)ss[e];
                    queues[((size_t)(m * NBKT + b)) * QCAP + slot] = pk;
                }
            }
        }
    }
}

// ================= bucket-base scan =================
__global__ void k_pscan(const int* __restrict__ gcur, int* __restrict__ pbase) {
    int t = threadIdx.x;
    if (t < MM) {
        int run = 0;
        for (int b = 0; b < NBKT; b++) {
            int L = gcur[t * NBKT + b]; if (L > QCAP) L = QCAP;
            pbase[t * NBKT + b] = run; run += L;
        }
    }
}

// ================= CSR build: one block owns one (m, bucket) =================
__global__ __launch_bounds__(512) void k_csr(const u64* __restrict__ queues,
                                             const int* __restrict__ gcur,
                                             const int* __restrict__ pbase,
                                             int* __restrict__ ofs,
                                             float* __restrict__ rs,
                                             int* __restrict__ sorted) {
    __shared__ int cnt[BSZ];
    __shared__ int wscan[8];
    const int m = blockIdx.y;
    const int b = blockIdx.x;
    const int tid = threadIdx.x;
    const int lane = tid & 63, w = tid >> 6;
    int qlen = gcur[m * NBKT + b]; if (qlen > QCAP) qlen = QCAP;
    const u64* q = queues + ((size_t)(m * NBKT + b)) * QCAP;
    const u64x2* q2 = (const u64x2*)q;
    const int dlo = b * BSZ;
    const int nd = min(dlo + BSZ, NN) - dlo;
    const int n2 = qlen >> 1;
    for (int i = tid; i < BSZ; i += 512) cnt[i] = 0;
    __syncthreads();
    for (int i = tid; i < n2; i += 512) {
        u64x2 e = q2[i];
        atomicAdd(&cnt[(int)(e.x >> 32) - dlo], 1);
        atomicAdd(&cnt[(int)(e.y >> 32) - dlo], 1);
    }
    if (tid == 0 && (qlen & 1))
        atomicAdd(&cnt[(int)(q[qlen - 1] >> 32) - dlo], 1);
    __syncthreads();
    const int c0 = tid * 2;
    int v0 = (c0 < BSZ) ? cnt[c0] : 0;
    int v1 = (c0 + 1 < BSZ) ? cnt[c0 + 1] : 0;
    int s = v0 + v1;
    int vv = s;
    for (int off = 1; off < 64; off <<= 1) { int t = __shfl_up(vv, off); if (lane >= off) vv += t; }
    if (lane == 63) wscan[w] = vv;
    __syncthreads();
    if (tid == 0) { int run = 0; for (int j = 0; j < 8; j++) { int t = wscan[j]; wscan[j] = run; run += t; } }
    __syncthreads();
    int excl = wscan[w] + vv - s;
    int g0 = pbase[m * NBKT + b] + excl;
    int g1 = g0 + v0;
    if (c0 < nd) {
        ofs[(size_t)m * (NN + 1) + dlo + c0] = g0;
        rs[(size_t)m * NN + dlo + c0] = rsqrtf((float)(v0 + 1));
    }
    if (c0 + 1 < nd) {
        ofs[(size_t)m * (NN + 1) + dlo + c0 + 1] = g1;
        rs[(size_t)m * NN + dlo + c0 + 1] = rsqrtf((float)(v1 + 1));
    }
    if (b == NBKT - 1 && tid == 0)
        ofs[(size_t)m * (NN + 1) + NN] = EE;
    __syncthreads();
    if (c0 < BSZ) cnt[c0] = g0;
    if (c0 + 1 < BSZ) cnt[c0 + 1] = g1;
    __syncthreads();
    int* srt = sorted + (size_t)m * EE;
    for (int i = tid; i < n2; i += 512) {
        u64x2 e = q2[i];
        int p0 = atomicAdd(&cnt[(int)(e.x >> 32) - dlo], 1);
        srt[p0] = (int)(e.x & 0xffffffffu);
        int p1 = atomicAdd(&cnt[(int)(e.y >> 32) - dlo], 1);
        srt[p1] = (int)(e.y & 0xffffffffu);
    }
    if (tid == 0 && (qlen & 1)) {
        u64 e = q[qlen - 1];
        int p0 = atomicAdd(&cnt[(int)(e >> 32) - dlo], 1);
        srt[p0] = (int)(e & 0xffffffffu);
    }
}

// ================= weight prep: fp32 -> bf16 MFMA B-fragment layout =================
__global__ __launch_bounds__(256) void k_prep(const float* __restrict__ We, const float* __restrict__ Wc,
                                              const float* __restrict__ Wd, const float* __restrict__ Ws,
                                              u16* __restrict__ wbe, u16* __restrict__ wbc,
                                              u16* __restrict__ wbd, u16* __restrict__ wbs) {
    int t = blockIdx.x * 256 + threadIdx.x;
    if (t >= 11776) return;
    bf16x8 val;
    u16* dst;
    if (t < 6144) {                       // enc
        int m = t >> 11, r = t & 2047;
        int nt = r >> 8, ks = (r >> 6) & 3, lane = r & 63;
        int n = nt * 16 + (lane & 15), h = n >> 6, o = n & 63;
        int kb = ks * 32 + (lane >> 4) * 8;
        const float* w = We + ((size_t)(m * 2 + h) * 128) * 64;
#pragma unroll
        for (int j = 0; j < 8; j++) val[j] = (short)f2b(w[(size_t)(kb + j) * 64 + o]);
        dst = wbe + ((size_t)m * 2048 + r) * 8;
    } else if (t < 9216) {                // conv
        int u = t - 6144;
        int m = u >> 10, r = u & 1023;
        int nt = r >> 7, ks = (r >> 6) & 1, lane = r & 63;
        int h = nt >> 2, o = (nt & 3) * 16 + (lane & 15);
        int kb = ks * 32 + (lane >> 4) * 8;
        const float* w = Wc + ((size_t)(m * 2 + h) * 64) * 64;
#pragma unroll
        for (int j = 0; j < 8; j++) val[j] = (short)f2b(w[(size_t)(kb + j) * 64 + o]);
        dst = wbc + ((size_t)m * 1024 + r) * 8;
    } else if (t < 10752) {               // dec
        int u = t - 9216;
        int m = u >> 9, r = u & 511;
        int nt = r >> 7, ks = (r >> 6) & 1, lane = r & 63;
        int h = nt >> 1, o = (nt & 1) * 16 + (lane & 15);
        int kb = ks * 32 + (lane >> 4) * 8;
        const float* w = Wd + ((size_t)(m * 2 + h) * 64) * 32;
#pragma unroll
        for (int j = 0; j < 8; j++) val[j] = (short)f2b(w[(size_t)(kb + j) * 32 + o]);
        dst = wbd + ((size_t)m * 512 + r) * 8;
    } else {                              // W_s
        int r = t - 10752;
        int nt = r >> 7, ks = (r >> 6) & 1, lane = r & 63;
        int n = nt * 16 + (lane & 15);
        int kb = ks * 32 + (lane >> 4) * 8;
#pragma unroll
        for (int j = 0; j < 8; j++) val[j] = (short)f2b(Ws[(size_t)(kb + j) * 128 + n]);
        dst = wbs + (size_t)r * 8;
    }
    *(bf16x8*)dst = val;
}

// ================= fused enc+conv: writes xw' = e4m3(64 * rs[row] * (h @ Wc)) =================
#define HLS 133
__global__ __launch_bounds__(256) void k_encconv(const float* __restrict__ x,
                                                 const u16* __restrict__ wbe_all,
                                                 const float* __restrict__ be_all,
                                                 const u16* __restrict__ wbc_all,
                                                 const float* __restrict__ rs_all,
                                                 u8* __restrict__ xw_all) {
    __shared__ float hl[64 * HLS];
    const int m = blockIdx.y;
    const int tid = threadIdx.x, lane = tid & 63, wave = tid >> 6;
    const int quad = lane >> 4, c16 = lane & 15;
    const int row = blockIdx.x * 64 + wave * 16 + c16;
    const bool ok = row < NN;
    const bf16x8* wbE = (const bf16x8*)(wbe_all + (size_t)m * 2048 * 8);
    const float* be = be_all + m * 2 * 64;
    const float* rs = rs_all + (size_t)m * NN;
    u8* xw = xw_all + (size_t)m * NN * 128;
    f32x4 zero = {0.f, 0.f, 0.f, 0.f};
    f32x4 acc[8];
#pragma unroll
    for (int nt = 0; nt < 8; nt++) acc[nt] = zero;
#pragma unroll
    for (int ks = 0; ks < 4; ks++) {
        bf16x8 a = {0, 0, 0, 0, 0, 0, 0, 0};
        if (ok) {
            const float* xp = x + (size_t)row * 128 + ks * 32 + quad * 8;
            float4 xa = *(const float4*)xp;
            float4 xb = *(const float4*)(xp + 4);
            a[0] = (short)f2b(xa.x); a[1] = (short)f2b(xa.y);
            a[2] = (short)f2b(xa.z); a[3] = (short)f2b(xa.w);
            a[4] = (short)f2b(xb.x); a[5] = (short)f2b(xb.y);
            a[6] = (short)f2b(xb.z); a[7] = (short)f2b(xb.w);
        }
#pragma unroll
        for (int nt = 0; nt < 8; nt++)
            acc[nt] = __builtin_amdgcn_mfma_f32_16x16x32_bf16(a, wbE[(nt * 4 + ks) * 64 + lane], acc[nt], 0, 0, 0);
    }
    const int rbl = wave * 16 + quad * 4;
#pragma unroll
    for (int nt = 0; nt < 8; nt++) {
        int col = nt * 16 + c16, hh = col >> 6, o = col & 63;
        float bias = be[hh * 64 + o];
#pragma unroll
        for (int j = 0; j < 4; j++) {
            int rl = rbl + j;
            int rg = blockIdx.x * 64 + rl;
            hl[rl * HLS + col] = (rg < NN) ? lrelu(acc[nt][j] + bias) : 0.f;
        }
    }
    __syncthreads();
    const bf16x8* wbC = (const bf16x8*)(wbc_all + (size_t)m * 1024 * 8);
    f32x4 cacc[8];
#pragma unroll
    for (int nt = 0; nt < 8; nt++) cacc[nt] = zero;
    const int rl = wave * 16 + c16;
#pragma unroll
    for (int ks = 0; ks < 2; ks++) {
        bf16x8 a0, a1;
        const float* hp = &hl[rl * HLS + ks * 32 + quad * 8];
#pragma unroll
        for (int j = 0; j < 8; j++) { a0[j] = (short)f2b(hp[j]); a1[j] = (short)f2b(hp[64 + j]); }
#pragma unroll
        for (int nt = 0; nt < 8; nt++)
            cacc[nt] = __builtin_amdgcn_mfma_f32_16x16x32_bf16(nt < 4 ? a0 : a1, wbC[(nt * 2 + ks) * 64 + lane], cacc[nt], 0, 0, 0);
    }
    float rsv[4];
#pragma unroll
    for (int j = 0; j < 4; j++) {
        int r = blockIdx.x * 64 + rbl + j;
        rsv[j] = (r < NN) ? rs[r] * 64.f : 0.f;
    }
#pragma unroll
    for (int nt = 0; nt < 8; nt++) {
        int col = nt * 16 + c16;
#pragma unroll
        for (int j = 0; j < 4; j++) {
            int r = blockIdx.x * 64 + rbl + j;
            if (r < NN) xw[(size_t)r * 128 + col] = f2e4hw(cacc[nt][j] * rsv[j]);
        }
    }
}

// decode 8 fp8 bytes (u64) into 4 f32x2 partial accumulators via hw cvt
__device__ __forceinline__ void acc_fp8x8(f32x2* acc, u64 w) {
    unsigned lo = (unsigned)w, hi = (unsigned)(w >> 32);
    acc[0] += __builtin_amdgcn_cvt_pk_f32_fp8(lo, false);
    acc[1] += __builtin_amdgcn_cvt_pk_f32_fp8(lo, true);
    acc[2] += __builtin_amdgcn_cvt_pk_f32_fp8(hi, false);
    acc[3] += __builtin_amdgcn_cvt_pk_f32_fp8(hi, true);
}

// ================= fused gather + post + score (pipelined gather, 8-wave epilogue) =================
__global__ __launch_bounds__(512) void k_gpost(const int* __restrict__ sorted_all,
                                               const int* __restrict__ ofs_all,
                                               const float* __restrict__ rs_all,
                                               const u8* __restrict__ xw_all,
                                               const float* __restrict__ bconv_all,
                                               const u16* __restrict__ wbd_all,
                                               const float* __restrict__ bdec_all,
                                               const u16* __restrict__ wbs,
                                               const float* __restrict__ bs,
                                               const float* __restrict__ qv,
                                               u16* __restrict__ z_all,
                                               float* __restrict__ score) {
    __shared__ u16 shm[64 * GLS];           // ggl (u16) / zl (float, stride 68) overlay
    __shared__ float spart[8];
    u16* ggl = shm;
    float* zl = (float*)shm;
    const int m = blockIdx.y;
    const int tid = threadIdx.x, lane = tid & 63, wave = tid >> 6;
    const int* sorted = sorted_all + (size_t)m * EE;
    const int* ofs = ofs_all + (size_t)m * (NN + 1);
    const float* rs = rs_all + (size_t)m * NN;
    const u8* xw = xw_all + (size_t)m * NN * 128;
    const float* bconv = bconv_all + m * 2 * 64;
    const float* bdec = bdec_all + m * 2 * 32;
    u16* z = z_all + (size_t)m * NN * 64;

    // ---- gather: 8 waves x 8 dsts; per dst one coalesced 16-index load -> 16 rows in flight ----
    const int p = lane >> 4, c = lane & 15;
    const int base = blockIdx.x * 64 + wave * 8;
    int ov = 0;
    {
        int ii = base + lane;
        if (lane < 9) ov = ofs[ii > NN ? NN : ii];
    }
    // batched first-16 index load for dst d (coalesced 64B; all 4 groups mirror it)
    auto loadidx = [&](int d) -> int {
        int bg = __shfl(ov, d);
        int dg = __shfl(ov, d + 1) - bg;
        if (base + d >= NN) return 0;
        return (c < dg) ? sorted[bg + c] : 0;
    };
    int idx_cur = loadidx(0);
    for (int d = 0; d < 8; d++) {
        const int dst = base + d;
        const int beg = __shfl(ov, d), end = __shfl(ov, d + 1);
        const int deg = end - beg;
        int idx_nxt = (d < 7) ? loadidx(d + 1) : 0;   // prefetch next dst's indices
        if (dst < NN) {
            // own row early (coalesced 128B/wave)
            u64 ow = *(const u64*)&xw[(size_t)dst * 128 + c * 8];
            f32x2 acc[4];
            acc[0] = 0.f; acc[1] = 0.f; acc[2] = 0.f; acc[3] = 0.f;
            // batch: 16 rows in flight across the wave
            u64 wv[4];
#pragma unroll
            for (int k = 0; k < 4; k++) {
                int e = p + 4 * k;
                int s = __shfl(idx_cur, e);
                wv[k] = (e < deg) ? *(const u64*)&xw[(size_t)s * 128 + c * 8] : 0ull;
            }
#pragma unroll
            for (int k = 0; k < 4; k++) acc_fp8x8(acc, wv[k]);   // zeros decode to +0
            // tail: deg > 16, old 4-deep path
            int j0 = beg + 16 + p;
            while (j0 < end) {
                int j1 = j0 + 4, j2 = j0 + 8, j3 = j0 + 12;
                bool h1 = j1 < end, h2 = j2 < end, h3 = j3 < end;
                int s0 = sorted[j0];
                int s1 = h1 ? sorted[j1] : s0;
                int s2 = h2 ? sorted[j2] : s0;
                int s3 = h3 ? sorted[j3] : s0;
                u64 w0 = *(const u64*)&xw[(size_t)s0 * 128 + c * 8];
                u64 w1 = h1 ? *(const u64*)&xw[(size_t)s1 * 128 + c * 8] : 0ull;
                u64 w2 = h2 ? *(const u64*)&xw[(size_t)s2 * 128 + c * 8] : 0ull;
                u64 w3 = h3 ? *(const u64*)&xw[(size_t)s3 * 128 + c * 8] : 0ull;
                acc_fp8x8(acc, w0);
                acc_fp8x8(acc, w1);
                acc_fp8x8(acc, w2);
                acc_fp8x8(acc, w3);
                j0 += 16;
            }
#pragma unroll
            for (int k = 0; k < 4; k++) {
                acc[k].x += __shfl_down(acc[k].x, 16);
                acc[k].y += __shfl_down(acc[k].y, 16);
                acc[k].x += __shfl_down(acc[k].x, 32);
                acc[k].y += __shfl_down(acc[k].y, 32);
            }
            if (p == 0) {
                acc_fp8x8(acc, ow);
                float mul = rs[dst] * (1.f / 64.f);
                u16x8 o;
#pragma unroll
                for (int k = 0; k < 4; k++) {
                    o[2 * k] = f2b(acc[k].x * mul);
                    o[2 * k + 1] = f2b(acc[k].y * mul);
                }
                *(u16x8*)&ggl[(wave * 8 + d) * GLS + c * 8] = o;
            }
        } else if (p == 0) {
            u16x8 o = {0, 0, 0, 0, 0, 0, 0, 0};
            *(u16x8*)&ggl[(wave * 8 + d) * GLS + c * 8] = o;
        }
        idx_cur = idx_nxt;
    }
    __syncthreads();

    // ---- post MFMA, all 8 waves: wave&3 = row group, wave>>2 = head ----
    f32x4 zero = {0.f, 0.f, 0.f, 0.f};
    const int quad = lane >> 4, c16 = lane & 15;
    const int wq = wave & 3, hi = wave >> 2;
    const int rl = wq * 16 + c16;
    const bf16x8* wd = (const bf16x8*)(wbd_all + (size_t)m * 512 * 8);
    f32x4 pacc[2];
    pacc[0] = zero; pacc[1] = zero;
#pragma unroll
    for (int ks = 0; ks < 2; ks++) {
        bf16x8 a;
        int k0 = ks * 32 + quad * 8;
        const u16* gp = &ggl[rl * GLS + hi * 64 + k0];
#pragma unroll
        for (int j = 0; j < 8; j++)
            a[j] = (short)f2b(lrelu(b2f(gp[j]) + bconv[hi * 64 + k0 + j]));
#pragma unroll
        for (int nt2 = 0; nt2 < 2; nt2++) {
            int nt = hi * 2 + nt2;
            pacc[nt2] = __builtin_amdgcn_mfma_f32_16x16x32_bf16(a, wd[(nt * 2 + ks) * 64 + lane], pacc[nt2], 0, 0, 0);
        }
    }
    __syncthreads();   // all ggl reads done; zl may overwrite
    {
        const int rbl = wq * 16 + quad * 4;
#pragma unroll
        for (int nt2 = 0; nt2 < 2; nt2++) {
            int nt = hi * 2 + nt2;
            int col = nt * 16 + c16, hh = col >> 5, o = col & 31;
            float bias = bdec[hh * 32 + o];
#pragma unroll
            for (int j = 0; j < 4; j++) {
                int rl2 = rbl + j;
                int rg = blockIdx.x * 64 + rl2;
                zl[rl2 * 68 + col] = (rg < NN) ? (pacc[nt2][j] + bias) : 0.f;
            }
        }
    }
    __syncthreads();

    // ---- z store (512 threads) + score MFMA (8 waves: wave>>2 picks nt half) ----
    {
        int rl2 = tid >> 3, cq = tid & 7;
        int rg = blockIdx.x * 64 + rl2;
        if (rg < NN) {
#pragma unroll
            for (int i = 0; i < 2; i++) {
                int c4 = (cq * 2 + i) * 4;
                float4 zv = *(const float4*)&zl[rl2 * 68 + c4];
                ushort4 o;
                o.x = f2b(zv.x); o.y = f2b(zv.y); o.z = f2b(zv.z); o.w = f2b(zv.w);
                *(ushort4*)&z[(size_t)rg * 64 + c4] = o;
            }
        }
    }
    float s = 0.f;
    {
        const bf16x8* wsb = (const bf16x8*)wbs;
        f32x4 sa[4];
#pragma unroll
        for (int nt2 = 0; nt2 < 4; nt2++) sa[nt2] = zero;
#pragma unroll
        for (int ks = 0; ks < 2; ks++) {
            bf16x8 a;
            const float* zp = &zl[rl * 68 + ks * 32 + quad * 8];
#pragma unroll
            for (int j = 0; j < 8; j++) a[j] = (short)f2b(zp[j]);
#pragma unroll
            for (int nt2 = 0; nt2 < 4; nt2++) {
                int nt = hi * 4 + nt2;
                sa[nt2] = __builtin_amdgcn_mfma_f32_16x16x32_bf16(a, wsb[(nt * 2 + ks) * 64 + lane], sa[nt2], 0, 0, 0);
            }
        }
        const int rbl = wq * 16 + quad * 4;
#pragma unroll
        for (int nt2 = 0; nt2 < 4; nt2++) {
            int nt = hi * 4 + nt2;
            int col = nt * 16 + c16;
            float qc = qv[col], bb = bs[col];
#pragma unroll
            for (int j = 0; j < 4; j++) {
                int rg = blockIdx.x * 64 + rbl + j;
                if (rg < NN) s += fast_tanh(sa[nt2][j] + bb) * qc;
            }
        }
#pragma unroll
        for (int off = 1; off < 64; off <<= 1) s += __shfl_xor(s, off);
    }
    if (lane == 0) spart[wave] = s;
    __syncthreads();
    if (tid == 0) {
        float t = spart[0] + spart[1] + spart[2] + spart[3]
                + spart[4] + spart[5] + spart[6] + spart[7];
        atomicAdd(&score[m], t);
    }
}

// ================= beta =================
__global__ void k_beta(const float* __restrict__ score, float* __restrict__ beta_ws,
                       float* __restrict__ out) {
    if (threadIdx.x == 0) {
        float s0 = score[0] / (float)NN, s1 = score[1] / (float)NN, s2 = score[2] / (float)NN;
        float mx = fmaxf(s0, fmaxf(s1, s2));
        float e0 = expf(s0 - mx), e1 = expf(s1 - mx), e2 = expf(s2 - mx);
        float inv = 1.f / (e0 + e1 + e2);
        beta_ws[0] = e0 * inv; beta_ws[1] = e1 * inv; beta_ws[2] = e2 * inv;
        out[800000] = e0 * inv; out[800001] = e1 * inv; out[800002] = e2 * inv;
    }
}

// ================= output: log_softmax((beta . z) @ W_o + b_o), z in bf16 =================
__global__ __launch_bounds__(256) void k_out(const u16* __restrict__ z,
                                             const float* __restrict__ beta,
                                             const float* __restrict__ Wo,
                                             const float* __restrict__ bo,
                                             float* __restrict__ out) {
    __shared__ float Zt[64 * 68];
    __shared__ float Wl[64 * 16];
    __shared__ float bl[16];
    const int tid = threadIdx.x, nbase = blockIdx.x * 64;
    float b0 = beta[0], b1 = beta[1], b2 = beta[2];
    for (int qq = tid; qq < 64 * 16; qq += 256) {
        int node = qq >> 4, k4 = qq & 15;
        int ng = nbase + node;
        float4 v = make_float4(0.f, 0.f, 0.f, 0.f);
        if (ng < NN) {
            ushort4 z0 = *(const ushort4*)&z[((size_t)0 * NN + ng) * 64 + k4 * 4];
            ushort4 z1 = *(const ushort4*)&z[((size_t)1 * NN + ng) * 64 + k4 * 4];
            ushort4 z2 = *(const ushort4*)&z[((size_t)2 * NN + ng) * 64 + k4 * 4];
            v.x = b0 * b2f(z0.x) + b1 * b2f(z1.x) + b2 * b2f(z2.x);
            v.y = b0 * b2f(z0.y) + b1 * b2f(z1.y) + b2 * b2f(z2.y);
            v.z = b0 * b2f(z0.z) + b1 * b2f(z1.z) + b2 * b2f(z2.z);
            v.w = b0 * b2f(z0.w) + b1 * b2f(z1.w) + b2 * b2f(z2.w);
        }
        *(float4*)&Zt[node * 68 + k4 * 4] = v;
    }
    for (int qq = tid; qq < 64 * 16 / 4; qq += 256)
        ((float4*)Wl)[qq] = ((const float4*)Wo)[qq];
    if (tid < 16) bl[tid] = bo[tid];
    __syncthreads();

    const int node = tid >> 2, cg = tid & 3;
    float4 a = make_float4(bl[cg * 4 + 0], bl[cg * 4 + 1], bl[cg * 4 + 2], bl[cg * 4 + 3]);
    for (int k = 0; k < 64; k++) {
        float zv = Zt[node * 68 + k];
        float4 w = *(const float4*)&Wl[k * 16 + cg * 4];
        a.x = fmaf(zv, w.x, a.x);
        a.y = fmaf(zv, w.y, a.y);
        a.z = fmaf(zv, w.z, a.z);
        a.w = fmaf(zv, w.w, a.w);
    }
    float mx = fmaxf(fmaxf(a.x, a.y), fmaxf(a.z, a.w));
    mx = fmaxf(mx, __shfl_xor(mx, 1));
    mx = fmaxf(mx, __shfl_xor(mx, 2));
    float sm = expf(a.x - mx) + expf(a.y - mx) + expf(a.z - mx) + expf(a.w - mx);
    sm += __shfl_xor(sm, 1);
    sm += __shfl_xor(sm, 2);
    float lse = mx + logf(sm);
    int ng = nbase + node;
    if (ng < NN) {
        float4 r = make_float4(a.x - lse, a.y - lse, a.z - lse, a.w - lse);
        *(float4*)&out[(size_t)ng * 16 + cg * 4] = r;
    }
}

extern "C" void kernel_launch(void* const* d_in, const int* in_sizes, int n_in,
                              void* d_out, int out_size, void* d_ws, size_t ws_size,
                              hipStream_t stream) {
    const float* x      = (const float*)d_in[0];
    const int*   ei     = (const int*)d_in[1];
    const float* W_enc  = (const float*)d_in[2];
    const float* b_enc  = (const float*)d_in[3];
    const float* W_conv = (const float*)d_in[4];
    const float* b_conv = (const float*)d_in[5];
    const float* W_dec  = (const float*)d_in[6];
    const float* b_dec  = (const float*)d_in[7];
    const float* W_s    = (const float*)d_in[8];
    const float* b_s    = (const float*)d_in[9];
    const float* qv     = (const float*)d_in[10];
    const float* W_o    = (const float*)d_in[11];
    const float* b_o    = (const float*)d_in[12];
    float* out = (float*)d_out;

    char* ws = (char*)d_ws;
    size_t off = 0;
    auto alloc = [&](size_t bytes) -> char* {
        char* p = ws + off;
        off = (off + bytes + 255) & ~(size_t)255;
        return p;
    };
    int*   row_ofs = (int*)alloc((size_t)MM * (NN + 1) * 4);
    float* rs      = (float*)alloc((size_t)MM * NN * 4);
    int*   sorted  = (int*)alloc((size_t)MM * EE * 4);
    u64*   queues  = (u64*)alloc((size_t)MM * NBKT * QCAP * 8);
    int*   gcur    = (int*)alloc((size_t)MM * NBKT * 4);
    int*   pbase   = (int*)alloc((size_t)MM * NBKT * 4);
    float* score   = (float*)alloc(64);
    float* beta_ws = (float*)alloc(64);
    u16*   wbe     = (u16*)alloc((size_t)MM * 2048 * 8 * 2);
    u16*   wbc     = (u16*)alloc((size_t)MM * 1024 * 8 * 2);
    u16*   wbd     = (u16*)alloc((size_t)MM * 512 * 8 * 2);
    u16*   wbs     = (u16*)alloc((size_t)1024 * 8 * 2);
    u8*    xw_buf  = (u8*)alloc((size_t)MM * NN * 128);
    u16*   z_buf   = (u16*)alloc((size_t)MM * NN * 64 * 2);

    hipMemsetAsync(gcur, 0, (size_t)MM * NBKT * 4, stream);
    hipMemsetAsync(score, 0, 16, stream);

    dim3 gbkt(BBLK, MM);
    dim3 gcsr(NBKT, MM);
    k_bucket<<<gbkt, 256, 0, stream>>>(ei, queues, gcur);
    k_pscan<<<1, 64, 0, stream>>>(gcur, pbase);
    k_csr<<<gcsr, 512, 0, stream>>>(queues, gcur, pbase, row_ofs, rs, sorted);
    k_prep<<<46, 256, 0, stream>>>(W_enc, W_conv, W_dec, W_s, wbe, wbc, wbd, wbs);

    const int GB = (NN + 63) / 64;   // 782
    dim3 gmm(GB, MM);
    k_encconv<<<gmm, 256, 0, stream>>>(x, wbe, b_enc, wbc, rs, xw_buf);
    k_gpost<<<gmm, 512, 0, stream>>>(sorted, row_ofs, rs, xw_buf,
                                     b_conv, wbd, b_dec, wbs, b_s, qv,
                                     z_buf, score);
    k_beta<<<1, 64, 0, stream>>>(score, beta_ws, out);
    k_out<<<GB, 256, 0, stream>>>(z_buf, beta_ws, W_o, b_o, out);
}